// Round 1
// baseline (159.536 us; speedup 1.0000x reference)
//
#include <hip/hip_runtime.h>
#include <math.h>

#define DELTA 0.1f

// One row = 4 floats = one float4. 2048 blocks x 256 threads, grid-stride.
__global__ __launch_bounds__(256) void ssim_loss_kernel(
    const float4* __restrict__ pred,
    const float4* __restrict__ target,
    double* __restrict__ accum,
    int N)
{
    int tid = blockIdx.x * blockDim.x + threadIdx.x;
    int stride = gridDim.x * blockDim.x;

    float local = 0.0f;
    for (int i = tid; i < N; i += stride) {
        float4 p = pred[i];
        float4 t = target[i];

        float mp = (p.x + p.y + p.z + p.w) * 0.25f;
        float mt = (t.x + t.y + t.z + t.w) * 0.25f;

        float dpx = p.x - mp, dpy = p.y - mp, dpz = p.z - mp, dpw = p.w - mp;
        float dtx = t.x - mt, dty = t.y - mt, dtz = t.z - mt, dtw = t.w - mt;

        const float inv = 1.0f / 3.0f;  // 1/(D-1)
        float vp  = (dpx*dpx + dpy*dpy + dpz*dpz + dpw*dpw) * inv;
        float vt  = (dtx*dtx + dty*dty + dtz*dtz + dtw*dtw) * inv;
        float cov = (dpx*dtx + dpy*dty + dpz*dtz + dpw*dtw) * inv;

        float a1 = 2.0f * mp * mt + DELTA;
        float a2 = 2.0f * cov + DELTA;
        float b1 = mp * mp + mt * mt + DELTA;
        float b2 = vp + vt + DELTA;

        float similar = (a1 * a2) / (b1 * b2 + DELTA);
        local += 1.0f - similar;
    }

    // Wave64 butterfly reduce.
    #pragma unroll
    for (int off = 32; off > 0; off >>= 1)
        local += __shfl_down(local, off, 64);

    __shared__ float wave_sums[4];  // 256 threads / 64 lanes
    int lane = threadIdx.x & 63;
    int wid  = threadIdx.x >> 6;
    if (lane == 0) wave_sums[wid] = local;
    __syncthreads();

    if (threadIdx.x == 0) {
        float s = wave_sums[0] + wave_sums[1] + wave_sums[2] + wave_sums[3];
        atomicAdd(accum, (double)s);  // device-scope, cross-XCD safe
    }
}

__global__ void ssim_finalize_kernel(const double* __restrict__ accum,
                                     float* __restrict__ out, int N)
{
    double mean = *accum / (double)N;
    float f = (float)mean;
    // Reference: NaN anywhere (inputs or loss) -> fallback == 1.0.
    // NaN inputs propagate into the sum, so this check covers it.
    if (isnan(f)) f = 1.0f;
    *out = f;
}

extern "C" void kernel_launch(void* const* d_in, const int* in_sizes, int n_in,
                              void* d_out, int out_size, void* d_ws, size_t ws_size,
                              hipStream_t stream)
{
    const float4* pred   = (const float4*)d_in[0];
    const float4* target = (const float4*)d_in[1];
    int N = in_sizes[0] / 4;  // rows

    double* accum = (double*)d_ws;
    hipMemsetAsync(d_ws, 0, sizeof(double), stream);  // ws re-poisoned to 0xAA each call

    const int block = 256;
    const int grid  = 2048;  // memory-bound: cap grid, grid-stride the rest
    ssim_loss_kernel<<<grid, block, 0, stream>>>(pred, target, accum, N);
    ssim_finalize_kernel<<<1, 1, 0, stream>>>(accum, (float*)d_out, N);
}